// Round 10
// baseline (2315.649 us; speedup 1.0000x reference)
//
// ===========================================================================
// R10 — OUTPUT IS FLOAT32 (eureka: harness label "bf16" is a literal; ref
// returns jnp.float32; all prior rounds wrote bf16 into a float buffer).
// Pipeline = R5 baseline semantics: XLA-correlation convs, convT = flipped
// correlation, interior-zero-dilation stride-2 upsample. fp32 compute,
// fp64 BN stats. Inputs fp32 (proven R1/R2/R3).
// ===========================================================================
#include <hip/hip_runtime.h>
#include <hip/hip_bf16.h>
#include <stdint.h>

// ---------------------------------------------------------------------------
// conv_rA: one thread per output element (n, co, l). Block = 256 consecutive
// l for one (n, co); this co's weights staged in LDS.
// MODE 0: stride-1 conv, runtime pad; WT=true reads ConvTranspose weights
//         (I,O,K) flipped -> equivalent stride-1 correlation.
// MODE 1: stride-2 downsample, K=2, pad=0: y[l] = sum_k x[2l+k] w[k]
// MODE 2: stride-2 transposed upsample, K=2: y[l] = x[l>>1] * w[i,o,l&1]
// STATS (fp64 atomics): sum -> stats[co], sumsq -> stats[CO+co].
// ---------------------------------------------------------------------------
template<int CI, int CO, int K, int MODE,
         bool WT, bool STATS, bool HAS_BIAS, bool HAS_ADD>
__global__ __launch_bounds__(256)
void conv_rA(const float* __restrict__ xin,
             const float* __restrict__ w,
             const float* __restrict__ bias,
             const float* __restrict__ addsrc,
             double* __restrict__ stats,
             float* __restrict__ yout,
             int Lin, int Lout, int pad)
{
    __shared__ float wl[CI * K];

    const int tid = threadIdx.x;
    const int co  = blockIdx.y;
    const int n   = blockIdx.z;
    const int l   = blockIdx.x * 256 + tid;

    for (int i = tid; i < CI * K; i += 256) {
        int ci = i / K;
        int k  = i - ci * K;
        int src;
        if (WT)             src = (ci * CO + co) * K + (K - 1 - k);
        else if (MODE == 2) src = (ci * CO + co) * K + k;
        else                src = (co * CI + ci) * K + k;
        wl[i] = w[src];
    }
    __syncthreads();

    float acc = HAS_BIAS ? bias[co] : 0.f;
    const float* xn = xin + (size_t)n * CI * Lin;

    if (MODE == 0) {
        for (int ci = 0; ci < CI; ++ci) {
            const float* xr = xn + ci * Lin;
            const float* wr = &wl[ci * K];
#pragma unroll
            for (int k = 0; k < K; ++k) {
                int xi = l + k - pad;
                float xv = (xi >= 0 && xi < Lin) ? xr[xi] : 0.f;
                acc += wr[k] * xv;
            }
        }
    } else if (MODE == 1) {
        for (int ci = 0; ci < CI; ++ci) {
            const float* xr = xn + ci * Lin;
            const float* wr = &wl[ci * K];
#pragma unroll
            for (int k = 0; k < K; ++k)
                acc += wr[k] * xr[2 * l + k];
        }
    } else {
        const int xi = l >> 1;
        const int k  = l & 1;
        for (int ci = 0; ci < CI; ++ci)
            acc += wl[ci * K + k] * xn[ci * Lin + xi];
    }

    const size_t o = ((size_t)n * CO + co) * Lout + l;
    if (HAS_ADD) acc += addsrc[o];

    yout[o] = acc;   // FLOAT32 output, always

    if (STATS) {
        __shared__ float sred[8];
        float s1 = acc, s2 = acc * acc;
#pragma unroll
        for (int m = 1; m < 64; m <<= 1) {
            s1 += __shfl_xor(s1, m, 64);
            s2 += __shfl_xor(s2, m, 64);
        }
        const int wv = tid >> 6;
        if ((tid & 63) == 0) { sred[wv] = s1; sred[4 + wv] = s2; }
        __syncthreads();
        if (tid == 0) {
            atomicAdd(&stats[co],      (double)(sred[0] + sred[1] + sred[2] + sred[3]));
            atomicAdd(&stats[CO + co], (double)(sred[4] + sred[5] + sred[6] + sred[7]));
        }
    }
}

// ---------------------------------------------------------------------------
__global__ void bnp_rA(const double* __restrict__ stats,
                       const float* __restrict__ g, const float* __restrict__ be,
                       float2* __restrict__ sc, int C, double invNL)
{
    int c = threadIdx.x;
    if (c >= C) return;
    double mu  = stats[c] * invNL;
    double var = stats[C + c] * invNL - mu * mu;
    double rs  = 1.0 / sqrt(var + 1e-5);
    double gv  = (double)g[c] * rs;
    double bv  = (double)be[c] - mu * gv;
    sc[c] = make_float2((float)gv, (float)bv);
}

__global__ __launch_bounds__(256)
void bna_rA(const float* __restrict__ x, const float2* __restrict__ sc,
            const float* __restrict__ addsrc, float* __restrict__ y,
            int C, int L, int relu, int n4)
{
    int i = blockIdx.x * 256 + threadIdx.x;
    if (i >= n4) return;
    int base = i * 4;
    int c = (base / L) % C;
    float2 s = sc[c];
    float4 xv = ((const float4*)x)[i];
    float4 r;
    r.x = xv.x * s.x + s.y;
    r.y = xv.y * s.x + s.y;
    r.z = xv.z * s.x + s.y;
    r.w = xv.w * s.x + s.y;
    if (relu) {
        r.x = fmaxf(r.x, 0.f); r.y = fmaxf(r.y, 0.f);
        r.z = fmaxf(r.z, 0.f); r.w = fmaxf(r.w, 0.f);
    }
    if (addsrc) {
        float4 av = ((const float4*)addsrc)[i];
        r.x += av.x; r.y += av.y; r.z += av.z; r.w += av.w;
    }
    ((float4*)y)[i] = r;
}

// ---------------------------------------------------------------------------
// VQ: 32768 rows x 64 dims vs 512 codes; strict < keeps first argmin.
// Writes hq codeword rows; accumulates sum of best distances (fp64).
// ---------------------------------------------------------------------------
__global__ __launch_bounds__(256)
void vq_rA(const float* __restrict__ z, const float* __restrict__ emb,
           float* __restrict__ hq, double* __restrict__ lossAcc)
{
    __shared__ float ws[128 * 64];
    const int tid = threadIdx.x;
    const int r   = blockIdx.x * 256 + tid;

    float zr[64];
    const float4* zp = (const float4*)(z + (size_t)r * 64);
#pragma unroll
    for (int q = 0; q < 16; ++q) {
        float4 v = zp[q];
        zr[4*q+0] = v.x; zr[4*q+1] = v.y; zr[4*q+2] = v.z; zr[4*q+3] = v.w;
    }

    float best = 3.4e38f;
    int   bj   = 0;
    for (int c0 = 0; c0 < 512; c0 += 128) {
        __syncthreads();
        for (int i = tid; i < 128 * 16; i += 256)
            ((float4*)ws)[i] = ((const float4*)(emb + c0 * 64))[i];
        __syncthreads();
        for (int j = 0; j < 128; ++j) {
            const float4* wp = (const float4*)&ws[j * 64];
            float d = 0.f;
#pragma unroll
            for (int q = 0; q < 16; ++q) {
                float4 wv = wp[q];
                float t0 = zr[4*q+0] - wv.x;
                float t1 = zr[4*q+1] - wv.y;
                float t2 = zr[4*q+2] - wv.z;
                float t3 = zr[4*q+3] - wv.w;
                d += t0*t0 + t1*t1 + t2*t2 + t3*t3;
            }
            if (d < best) { best = d; bj = c0 + j; }
        }
    }

    const float* ep = emb + (size_t)bj * 64;
    float* hp = hq + (size_t)r * 64;
#pragma unroll
    for (int t = 0; t < 64; ++t) hp[t] = ep[t];

    float s = best;
#pragma unroll
    for (int m = 1; m < 64; m <<= 1) s += __shfl_xor(s, m, 64);
    if ((tid & 63) == 0) atomicAdd(lossAcc, (double)s);
}

__global__ void zd_rA(double* p, int n) {
    int i = blockIdx.x * 256 + threadIdx.x;
    if (i < n) p[i] = 0.0;
}

__global__ void wsguard_rA(float* p, int n) {
    int i = blockIdx.x * 256 + threadIdx.x;
    if (i < n) p[i] = 1000.0f;
}

// losses -> FLOAT32 slots at the end of the output tensor
__global__ void lossfin_rA(const double* acc, float* out) {
    float m = (float)(acc[0] * (1.0 / 32768.0));
    out[2097152] = m;   // commit_loss
    out[2097153] = m;   // vq_loss (identical forward value)
}

extern "C" void kernel_launch(void* const* d_in, const int* in_sizes, int n_in,
                              void* d_out, int out_size, void* d_ws, size_t ws_size,
                              hipStream_t stream)
{
    const size_t NEED = (size_t)3 * 4194304 * 4 + 2305 * 8 + 1152 * 8 + 64;
    if (ws_size < NEED) {
        wsguard_rA<<<dim3((out_size + 255) / 256), 256, 0, stream>>>((float*)d_out, out_size);
        return;
    }

    const float* x        = (const float*)d_in[0];
    const float* w_conv   = (const float*)d_in[1];
    const float* b_conv   = (const float*)d_in[2];
    const float* g_conv   = (const float*)d_in[3];
    const float* be_conv  = (const float*)d_in[4];
    const float* w_r1     = (const float*)d_in[5];
    const float* b_r1     = (const float*)d_in[6];
    const float* g_r1     = (const float*)d_in[7];
    const float* be_r1    = (const float*)d_in[8];
    const float* w_ds1    = (const float*)d_in[9];
    const float* b_ds1    = (const float*)d_in[10];
    const float* w_r2     = (const float*)d_in[11];
    const float* b_r2     = (const float*)d_in[12];
    const float* g_r2     = (const float*)d_in[13];
    const float* be_r2    = (const float*)d_in[14];
    const float* w_1to2   = (const float*)d_in[15];
    const float* w_ds2    = (const float*)d_in[16];
    const float* b_ds2    = (const float*)d_in[17];
    const float* embed_w  = (const float*)d_in[18];
    const float* w_us2    = (const float*)d_in[19];
    const float* b_us2    = (const float*)d_in[20];
    const float* w_dr2    = (const float*)d_in[21];
    const float* b_dr2    = (const float*)d_in[22];
    const float* g_dr2    = (const float*)d_in[23];
    const float* be_dr2   = (const float*)d_in[24];
    const float* w_2to1   = (const float*)d_in[25];
    const float* w_us1    = (const float*)d_in[26];
    const float* b_us1    = (const float*)d_in[27];
    const float* w_dr1    = (const float*)d_in[28];
    const float* b_dr1    = (const float*)d_in[29];
    const float* g_dr1    = (const float*)d_in[30];
    const float* be_dr1   = (const float*)d_in[31];
    const float* w_deconv = (const float*)d_in[32];
    const float* b_deconv = (const float*)d_in[33];

    float* out = (float*)d_out;

    float*  B0 = (float*)d_ws;
    float*  B1 = B0 + 4194304;
    float*  B2 = B1 + 4194304;
    double* SD = (double*)(B2 + 4194304);   // 9 slots x 256 + 1 loss
    double* lossAcc = SD + 9 * 256;
    float2* SC = (float2*)(SD + 2305);      // 9 slots x 128

    const int N = 64;
    const double i64k = 1.0 / 65536.0;
    const double i32k = 1.0 / 32768.0;

    zd_rA<<<dim3(10), 256, 0, stream>>>(SD, 9 * 256 + 1);

    // ---- encoder ----
    conv_rA<32,64,7,0, false,true,true,false>
        <<<dim3(4, 64, N), 256, 0, stream>>>(x, w_conv, b_conv, nullptr, SD+0*256, B0, 1024, 1024, 3);
    bnp_rA<<<1, 128, 0, stream>>>(SD+0*256, g_conv, be_conv, SC+0*128, 64, i64k);
    bna_rA<<<dim3(4096), 256, 0, stream>>>(B0, SC+0*128, nullptr, B0, 64, 1024, 0, 1048576);

    conv_rA<64,64,3,0, false,true,true,false>
        <<<dim3(4, 64, N), 256, 0, stream>>>(B0, w_r1, b_r1, nullptr, SD+1*256, B1, 1024, 1024, 1);
    bnp_rA<<<1, 128, 0, stream>>>(SD+1*256, g_r1, be_r1, SC+1*128, 64, i64k);
    bna_rA<<<dim3(4096), 256, 0, stream>>>(B1, SC+1*128, nullptr, B1, 64, 1024, 1, 1048576);

    conv_rA<64,64,3,0, false,true,true,false>
        <<<dim3(4, 64, N), 256, 0, stream>>>(B1, w_r1+12288, b_r1+64, nullptr, SD+2*256, B2, 1024, 1024, 1);
    bnp_rA<<<1, 128, 0, stream>>>(SD+2*256, g_r1+64, be_r1+64, SC+2*128, 64, i64k);
    bna_rA<<<dim3(4096), 256, 0, stream>>>(B2, SC+2*128, nullptr, B2, 64, 1024, 1, 1048576);

    conv_rA<64,64,3,0, false,true,true,false>
        <<<dim3(4, 64, N), 256, 0, stream>>>(B2, w_r1+24576, b_r1+128, nullptr, SD+3*256, B1, 1024, 1024, 1);
    bnp_rA<<<1, 128, 0, stream>>>(SD+3*256, g_r1+128, be_r1+128, SC+3*128, 64, i64k);
    bna_rA<<<dim3(4096), 256, 0, stream>>>(B1, SC+3*128, B0, B0, 64, 1024, 0, 1048576);

    conv_rA<64,64,2,1, false,false,true,false>
        <<<dim3(2, 64, N), 256, 0, stream>>>(B0, w_ds1, b_ds1, nullptr, nullptr, B1, 1024, 512, 0);

    conv_rA<64,128,3,0, false,true,true,false>
        <<<dim3(2, 128, N), 256, 0, stream>>>(B1, w_r2, b_r2, nullptr, SD+4*256, B2, 512, 512, 1);
    bnp_rA<<<1, 128, 0, stream>>>(SD+4*256, g_r2, be_r2, SC+4*128, 128, i32k);
    bna_rA<<<dim3(4096), 256, 0, stream>>>(B2, SC+4*128, nullptr, B2, 128, 512, 0, 1048576);

    conv_rA<64,128,1,0, false,false,false,true>
        <<<dim3(2, 128, N), 256, 0, stream>>>(B1, w_1to2, nullptr, B2, nullptr, B0, 512, 512, 0);

    conv_rA<128,128,2,1, false,false,true,false>
        <<<dim3(1, 128, N), 256, 0, stream>>>(B0, w_ds2, b_ds2, nullptr, nullptr, B1, 512, 256, 0);

    // ---- vector quantization ----
    vq_rA<<<dim3(128), 256, 0, stream>>>(B1, embed_w, B2, lossAcc);
    lossfin_rA<<<1, 1, 0, stream>>>(lossAcc, out);

    // ---- decoder ----
    conv_rA<128,128,2,2, false,false,true,false>
        <<<dim3(2, 128, N), 256, 0, stream>>>(B2, w_us2, b_us2, nullptr, nullptr, B0, 256, 512, 0);

    conv_rA<128,64,3,0, true,true,true,false>
        <<<dim3(2, 64, N), 256, 0, stream>>>(B0, w_dr2, b_dr2, nullptr, SD+5*256, B1, 512, 512, 1);
    bnp_rA<<<1, 128, 0, stream>>>(SD+5*256, g_dr2, be_dr2, SC+5*128, 64, i32k);
    bna_rA<<<dim3(2048), 256, 0, stream>>>(B1, SC+5*128, nullptr, B1, 64, 512, 0, 524288);

    conv_rA<128,64,1,0, false,false,false,true>
        <<<dim3(2, 64, N), 256, 0, stream>>>(B0, w_2to1, nullptr, B1, nullptr, B2, 512, 512, 0);

    conv_rA<64,64,2,2, false,false,true,false>
        <<<dim3(4, 64, N), 256, 0, stream>>>(B2, w_us1, b_us1, nullptr, nullptr, B0, 512, 1024, 0);

    conv_rA<64,64,3,0, true,true,true,false>
        <<<dim3(4, 64, N), 256, 0, stream>>>(B0, w_dr1, b_dr1, nullptr, SD+6*256, B1, 1024, 1024, 1);
    bnp_rA<<<1, 128, 0, stream>>>(SD+6*256, g_dr1, be_dr1, SC+6*128, 64, i64k);
    bna_rA<<<dim3(4096), 256, 0, stream>>>(B1, SC+6*128, nullptr, B1, 64, 1024, 1, 1048576);

    conv_rA<64,64,3,0, true,true,true,false>
        <<<dim3(4, 64, N), 256, 0, stream>>>(B1, w_dr1+12288, b_dr1+64, nullptr, SD+7*256, B2, 1024, 1024, 1);
    bnp_rA<<<1, 128, 0, stream>>>(SD+7*256, g_dr1+64, be_dr1+64, SC+7*128, 64, i64k);
    bna_rA<<<dim3(4096), 256, 0, stream>>>(B2, SC+7*128, nullptr, B2, 64, 1024, 1, 1048576);

    conv_rA<64,64,3,0, true,true,true,false>
        <<<dim3(4, 64, N), 256, 0, stream>>>(B2, w_dr1+24576, b_dr1+128, nullptr, SD+8*256, B1, 1024, 1024, 1);
    bnp_rA<<<1, 128, 0, stream>>>(SD+8*256, g_dr1+128, be_dr1+128, SC+8*128, 64, i64k);
    bna_rA<<<dim3(4096), 256, 0, stream>>>(B1, SC+8*128, B0, B0, 64, 1024, 0, 1048576);

    // final deconv: convT K=7 pad=3 -> (64,32,1024), FLOAT32 out
    conv_rA<64,32,7,0, true,false,true,false>
        <<<dim3(4, 32, N), 256, 0, stream>>>(B0, w_deconv, b_deconv, nullptr, nullptr, out, 1024, 1024, 3);
}

// Round 11
// 1434.259 us; speedup vs baseline: 1.6145x; 1.6145x over previous
//
// ===========================================================================
// R11 — performance round. Same numerics as R10 (fp32 compute, fp64 stats,
// identical accumulation orders), restructured for parallelism:
//  * VQ: 512 blocks, 4 lanes/row, bit-identical distances, shuffle argmin.
//  * Convs: LDS-tiled (x tile + weights), 256 thr = COB co x LT l-groups.
// ===========================================================================
#include <hip/hip_runtime.h>
#include <hip/hip_bf16.h>
#include <stdint.h>

// ---------------------------------------------------------------------------
// Tiled conv. MODE 0: stride-1 (pad runtime), WT=true: ConvTranspose (I,O,K)
// flipped. MODE 1: stride-2 downsample K=2. MODE 2: stride-2 transposed
// upsample K=2. Block: 256 thr = COB co x LT(=256/COB) l-groups, TLT=TL/LT
// outputs/thread. Accumulation order per output: ci-major, k-inner (bit-
// identical to R10's one-thread-per-output kernel).
// ---------------------------------------------------------------------------
template<int CI, int CO, int K, int MODE, int TL, int COB,
         bool WT, bool STATS, bool HAS_BIAS, bool HAS_ADD>
__global__ __launch_bounds__(256)
void conv_rB(const float* __restrict__ xin,
             const float* __restrict__ w,
             const float* __restrict__ bias,
             const float* __restrict__ addsrc,
             double* __restrict__ stats,
             float* __restrict__ yout,
             int Lin, int Lout, int pad)
{
    constexpr int LT   = 256 / COB;
    constexpr int TLT  = TL / LT;
    constexpr int SPAN = (MODE == 0) ? (TL + K - 1)
                       : (MODE == 1) ? ((TL - 1) * 2 + K)
                       : (TL / 2);
    constexpr int SPANP = (SPAN + 3) & ~3;
    constexpr int WN    = COB * CI * K;

    __shared__ float xs[CI * SPANP];
    __shared__ float wl[WN];   // [ci][k][co_l]

    const int tid    = threadIdx.x;
    const int ltile  = blockIdx.x;
    const int n      = blockIdx.y;
    const int coBase = blockIdx.z * COB;

    for (int i = tid; i < WN; i += 256) {
        int ci   = i / (K * COB);
        int rem  = i - ci * (K * COB);
        int k    = rem / COB;
        int co_l = rem - k * COB;
        int co   = coBase + co_l;
        int src;
        if (WT)             src = (ci * CO + co) * K + (K - 1 - k);
        else if (MODE == 2) src = (ci * CO + co) * K + k;
        else                src = (co * CI + ci) * K + k;
        wl[i] = w[src];
    }

    int x0;
    if (MODE == 0)      x0 = ltile * TL - pad;
    else if (MODE == 1) x0 = ltile * TL * 2;
    else                x0 = ltile * (TL / 2);
    for (int i = tid; i < CI * SPAN; i += 256) {
        int ci = i / SPAN;
        int s  = i - ci * SPAN;
        int xl = x0 + s;
        float v = 0.f;
        if (xl >= 0 && xl < Lin) v = xin[((size_t)n * CI + ci) * Lin + xl];
        xs[ci * SPANP + s] = v;
    }
    __syncthreads();

    const int co_l  = tid / LT;
    const int co    = coBase + co_l;
    const int loOff = (tid % LT) * TLT;

    float acc[TLT];
#pragma unroll
    for (int j = 0; j < TLT; ++j) acc[j] = HAS_BIAS ? bias[co] : 0.f;

    constexpr int XR = (MODE == 0) ? (TLT + K - 1)
                     : (MODE == 1) ? ((TLT - 1) * 2 + K)
                     : (TLT / 2);

    for (int ci = 0; ci < CI; ++ci) {
        float xr[XR];
        const int xb = ci * SPANP + ((MODE == 1) ? loOff * 2
                                   : (MODE == 2) ? (loOff / 2) : loOff);
#pragma unroll
        for (int t = 0; t < XR; ++t) xr[t] = xs[xb + t];
        if (MODE == 2) {
            float w0 = wl[(ci * 2 + 0) * COB + co_l];
            float w1 = wl[(ci * 2 + 1) * COB + co_l];
#pragma unroll
            for (int j = 0; j < TLT; ++j)
                acc[j] += ((j & 1) ? w1 : w0) * xr[j >> 1];
        } else {
#pragma unroll
            for (int k = 0; k < K; ++k) {
                float wk = wl[(ci * K + k) * COB + co_l];
#pragma unroll
                for (int j = 0; j < TLT; ++j)
                    acc[j] += wk * xr[((MODE == 1) ? 2 * j : j) + k];
            }
        }
    }

    const int lo0   = ltile * TL + loOff;
    const size_t obase = ((size_t)n * CO + co) * Lout + lo0;

    if (HAS_ADD) {
#pragma unroll
        for (int j = 0; j < TLT; ++j) acc[j] += addsrc[obase + j];
    }

#pragma unroll
    for (int j = 0; j < TLT; ++j) yout[obase + j] = acc[j];

    if (STATS) {
        float s1 = 0.f, s2 = 0.f;
#pragma unroll
        for (int j = 0; j < TLT; ++j) { s1 += acc[j]; s2 += acc[j] * acc[j]; }
#pragma unroll
        for (int m = 1; m < LT; m <<= 1) {
            s1 += __shfl_xor(s1, m, 64);
            s2 += __shfl_xor(s2, m, 64);
        }
        if ((tid & (LT - 1)) == 0) {
            atomicAdd(&stats[co],      (double)s1);
            atomicAdd(&stats[CO + co], (double)s2);
        }
    }
}

// ---------------------------------------------------------------------------
__global__ void bnp_rB(const double* __restrict__ stats,
                       const float* __restrict__ g, const float* __restrict__ be,
                       float2* __restrict__ sc, int C, double invNL)
{
    int c = threadIdx.x;
    if (c >= C) return;
    double mu  = stats[c] * invNL;
    double var = stats[C + c] * invNL - mu * mu;
    double rs  = 1.0 / sqrt(var + 1e-5);
    double gv  = (double)g[c] * rs;
    double bv  = (double)be[c] - mu * gv;
    sc[c] = make_float2((float)gv, (float)bv);
}

__global__ __launch_bounds__(256)
void bna_rB(const float* __restrict__ x, const float2* __restrict__ sc,
            const float* __restrict__ addsrc, float* __restrict__ y,
            int C, int L, int relu, int n4)
{
    int i = blockIdx.x * 256 + threadIdx.x;
    if (i >= n4) return;
    int base = i * 4;
    int c = (base / L) % C;
    float2 s = sc[c];
    float4 xv = ((const float4*)x)[i];
    float4 r;
    r.x = xv.x * s.x + s.y;
    r.y = xv.y * s.x + s.y;
    r.z = xv.z * s.x + s.y;
    r.w = xv.w * s.x + s.y;
    if (relu) {
        r.x = fmaxf(r.x, 0.f); r.y = fmaxf(r.y, 0.f);
        r.z = fmaxf(r.z, 0.f); r.w = fmaxf(r.w, 0.f);
    }
    if (addsrc) {
        float4 av = ((const float4*)addsrc)[i];
        r.x += av.x; r.y += av.y; r.z += av.z; r.w += av.w;
    }
    ((float4*)y)[i] = r;
}

// ---------------------------------------------------------------------------
// VQ: 512 blocks x 256 thr; 64 rows/block, 4 lanes/row; each lane scans 32
// codes per 128-code chunk (distance expression bit-identical to R10), then
// butterfly (d,j) combine with first-argmin tie-break.
// ---------------------------------------------------------------------------
__global__ __launch_bounds__(256)
void vq_rB(const float* __restrict__ z, const float* __restrict__ emb,
           float* __restrict__ hq, double* __restrict__ lossAcc)
{
    __shared__ float ws[128 * 64];
    const int tid  = threadIdx.x;
    const int sub  = tid & 3;
    const int r    = blockIdx.x * 64 + (tid >> 2);

    float zr[64];
    const float4* zp = (const float4*)(z + (size_t)r * 64);
#pragma unroll
    for (int q = 0; q < 16; ++q) {
        float4 v = zp[q];
        zr[4*q+0] = v.x; zr[4*q+1] = v.y; zr[4*q+2] = v.z; zr[4*q+3] = v.w;
    }

    float best = 3.4e38f;
    int   bj   = 0;
    for (int c0 = 0; c0 < 512; c0 += 128) {
        __syncthreads();
        for (int i = tid; i < 128 * 16; i += 256)
            ((float4*)ws)[i] = ((const float4*)(emb + c0 * 64))[i];
        __syncthreads();
        const int jb = sub * 32;
        for (int jj = 0; jj < 32; ++jj) {
            const int j = jb + jj;
            const float4* wp = (const float4*)&ws[j * 64];
            float d = 0.f;
#pragma unroll
            for (int q = 0; q < 16; ++q) {
                float4 wv = wp[q];
                float t0 = zr[4*q+0] - wv.x;
                float t1 = zr[4*q+1] - wv.y;
                float t2 = zr[4*q+2] - wv.z;
                float t3 = zr[4*q+3] - wv.w;
                d += t0*t0 + t1*t1 + t2*t2 + t3*t3;
            }
            if (d < best) { best = d; bj = c0 + j; }
        }
    }

    // combine across the 4 lanes of this row (first-argmin tie-break)
#pragma unroll
    for (int m = 1; m < 4; m <<= 1) {
        float od = __shfl_xor(best, m, 64);
        int   oj = __shfl_xor(bj,   m, 64);
        if (od < best || (od == best && oj < bj)) { best = od; bj = oj; }
    }

    // cooperative hq write: each lane writes 16 dims
    const float4* ep = (const float4*)(emb + (size_t)bj * 64);
    float4* hp = (float4*)(hq + (size_t)r * 64);
#pragma unroll
    for (int q = 0; q < 4; ++q) hp[sub * 4 + q] = ep[sub * 4 + q];

    // loss: one contribution per row
    float s = (sub == 0) ? best : 0.f;
#pragma unroll
    for (int m = 1; m < 64; m <<= 1) s += __shfl_xor(s, m, 64);
    if ((tid & 63) == 0) atomicAdd(lossAcc, (double)s);
}

__global__ void zd_rB(double* p, int n) {
    int i = blockIdx.x * 256 + threadIdx.x;
    if (i < n) p[i] = 0.0;
}

__global__ void wsguard_rB(float* p, int n) {
    int i = blockIdx.x * 256 + threadIdx.x;
    if (i < n) p[i] = 1000.0f;
}

__global__ void lossfin_rB(const double* acc, float* out) {
    float m = (float)(acc[0] * (1.0 / 32768.0));
    out[2097152] = m;   // commit_loss
    out[2097153] = m;   // vq_loss
}

extern "C" void kernel_launch(void* const* d_in, const int* in_sizes, int n_in,
                              void* d_out, int out_size, void* d_ws, size_t ws_size,
                              hipStream_t stream)
{
    const size_t NEED = (size_t)3 * 4194304 * 4 + 2305 * 8 + 1152 * 8 + 64;
    if (ws_size < NEED) {
        wsguard_rB<<<dim3((out_size + 255) / 256), 256, 0, stream>>>((float*)d_out, out_size);
        return;
    }

    const float* x        = (const float*)d_in[0];
    const float* w_conv   = (const float*)d_in[1];
    const float* b_conv   = (const float*)d_in[2];
    const float* g_conv   = (const float*)d_in[3];
    const float* be_conv  = (const float*)d_in[4];
    const float* w_r1     = (const float*)d_in[5];
    const float* b_r1     = (const float*)d_in[6];
    const float* g_r1     = (const float*)d_in[7];
    const float* be_r1    = (const float*)d_in[8];
    const float* w_ds1    = (const float*)d_in[9];
    const float* b_ds1    = (const float*)d_in[10];
    const float* w_r2     = (const float*)d_in[11];
    const float* b_r2     = (const float*)d_in[12];
    const float* g_r2     = (const float*)d_in[13];
    const float* be_r2    = (const float*)d_in[14];
    const float* w_1to2   = (const float*)d_in[15];
    const float* w_ds2    = (const float*)d_in[16];
    const float* b_ds2    = (const float*)d_in[17];
    const float* embed_w  = (const float*)d_in[18];
    const float* w_us2    = (const float*)d_in[19];
    const float* b_us2    = (const float*)d_in[20];
    const float* w_dr2    = (const float*)d_in[21];
    const float* b_dr2    = (const float*)d_in[22];
    const float* g_dr2    = (const float*)d_in[23];
    const float* be_dr2   = (const float*)d_in[24];
    const float* w_2to1   = (const float*)d_in[25];
    const float* w_us1    = (const float*)d_in[26];
    const float* b_us1    = (const float*)d_in[27];
    const float* w_dr1    = (const float*)d_in[28];
    const float* b_dr1    = (const float*)d_in[29];
    const float* g_dr1    = (const float*)d_in[30];
    const float* be_dr1   = (const float*)d_in[31];
    const float* w_deconv = (const float*)d_in[32];
    const float* b_deconv = (const float*)d_in[33];

    float* out = (float*)d_out;

    float*  B0 = (float*)d_ws;
    float*  B1 = B0 + 4194304;
    float*  B2 = B1 + 4194304;
    double* SD = (double*)(B2 + 4194304);
    double* lossAcc = SD + 9 * 256;
    float2* SC = (float2*)(SD + 2305);

    const int N = 64;
    const double i64k = 1.0 / 65536.0;
    const double i32k = 1.0 / 32768.0;

    zd_rB<<<dim3(10), 256, 0, stream>>>(SD, 9 * 256 + 1);

    // ---- encoder ----
    conv_rB<32,64,7,0,64,32, false,true,true,false>
        <<<dim3(16, N, 2), 256, 0, stream>>>(x, w_conv, b_conv, nullptr, SD+0*256, B0, 1024, 1024, 3);
    bnp_rB<<<1, 128, 0, stream>>>(SD+0*256, g_conv, be_conv, SC+0*128, 64, i64k);
    bna_rB<<<dim3(4096), 256, 0, stream>>>(B0, SC+0*128, nullptr, B0, 64, 1024, 0, 1048576);

    conv_rB<64,64,3,0,64,32, false,true,true,false>
        <<<dim3(16, N, 2), 256, 0, stream>>>(B0, w_r1, b_r1, nullptr, SD+1*256, B1, 1024, 1024, 1);
    bnp_rB<<<1, 128, 0, stream>>>(SD+1*256, g_r1, be_r1, SC+1*128, 64, i64k);
    bna_rB<<<dim3(4096), 256, 0, stream>>>(B1, SC+1*128, nullptr, B1, 64, 1024, 1, 1048576);

    conv_rB<64,64,3,0,64,32, false,true,true,false>
        <<<dim3(16, N, 2), 256, 0, stream>>>(B1, w_r1+12288, b_r1+64, nullptr, SD+2*256, B2, 1024, 1024, 1);
    bnp_rB<<<1, 128, 0, stream>>>(SD+2*256, g_r1+64, be_r1+64, SC+2*128, 64, i64k);
    bna_rB<<<dim3(4096), 256, 0, stream>>>(B2, SC+2*128, nullptr, B2, 64, 1024, 1, 1048576);

    conv_rB<64,64,3,0,64,32, false,true,true,false>
        <<<dim3(16, N, 2), 256, 0, stream>>>(B2, w_r1+24576, b_r1+128, nullptr, SD+3*256, B1, 1024, 1024, 1);
    bnp_rB<<<1, 128, 0, stream>>>(SD+3*256, g_r1+128, be_r1+128, SC+3*128, 64, i64k);
    bna_rB<<<dim3(4096), 256, 0, stream>>>(B1, SC+3*128, B0, B0, 64, 1024, 0, 1048576);

    conv_rB<64,64,2,1,32,32, false,false,true,false>
        <<<dim3(16, N, 2), 256, 0, stream>>>(B0, w_ds1, b_ds1, nullptr, nullptr, B1, 1024, 512, 0);

    conv_rB<64,128,3,0,64,32, false,true,true,false>
        <<<dim3(8, N, 4), 256, 0, stream>>>(B1, w_r2, b_r2, nullptr, SD+4*256, B2, 512, 512, 1);
    bnp_rB<<<1, 128, 0, stream>>>(SD+4*256, g_r2, be_r2, SC+4*128, 128, i32k);
    bna_rB<<<dim3(4096), 256, 0, stream>>>(B2, SC+4*128, nullptr, B2, 128, 512, 0, 1048576);

    conv_rB<64,128,1,0,64,32, false,false,false,true>
        <<<dim3(8, N, 4), 256, 0, stream>>>(B1, w_1to2, nullptr, B2, nullptr, B0, 512, 512, 0);

    conv_rB<128,128,2,1,32,16, false,false,true,false>
        <<<dim3(8, N, 8), 256, 0, stream>>>(B0, w_ds2, b_ds2, nullptr, nullptr, B1, 512, 256, 0);

    // ---- vector quantization ----
    vq_rB<<<dim3(512), 256, 0, stream>>>(B1, embed_w, B2, lossAcc);
    lossfin_rB<<<1, 1, 0, stream>>>(lossAcc, out);

    // ---- decoder ----
    conv_rB<128,128,2,2,64,32, false,false,true,false>
        <<<dim3(8, N, 4), 256, 0, stream>>>(B2, w_us2, b_us2, nullptr, nullptr, B0, 256, 512, 0);

    conv_rB<128,64,3,0,64,16, true,true,true,false>
        <<<dim3(8, N, 4), 256, 0, stream>>>(B0, w_dr2, b_dr2, nullptr, SD+5*256, B1, 512, 512, 1);
    bnp_rB<<<1, 128, 0, stream>>>(SD+5*256, g_dr2, be_dr2, SC+5*128, 64, i32k);
    bna_rB<<<dim3(2048), 256, 0, stream>>>(B1, SC+5*128, nullptr, B1, 64, 512, 0, 524288);

    conv_rB<128,64,1,0,64,32, false,false,false,true>
        <<<dim3(8, N, 2), 256, 0, stream>>>(B0, w_2to1, nullptr, B1, nullptr, B2, 512, 512, 0);

    conv_rB<64,64,2,2,64,32, false,false,true,false>
        <<<dim3(16, N, 2), 256, 0, stream>>>(B2, w_us1, b_us1, nullptr, nullptr, B0, 512, 1024, 0);

    conv_rB<64,64,3,0,64,32, true,true,true,false>
        <<<dim3(16, N, 2), 256, 0, stream>>>(B0, w_dr1, b_dr1, nullptr, SD+6*256, B1, 1024, 1024, 1);
    bnp_rB<<<1, 128, 0, stream>>>(SD+6*256, g_dr1, be_dr1, SC+6*128, 64, i64k);
    bna_rB<<<dim3(4096), 256, 0, stream>>>(B1, SC+6*128, nullptr, B1, 64, 1024, 1, 1048576);

    conv_rB<64,64,3,0,64,32, true,true,true,false>
        <<<dim3(16, N, 2), 256, 0, stream>>>(B1, w_dr1+12288, b_dr1+64, nullptr, SD+7*256, B2, 1024, 1024, 1);
    bnp_rB<<<1, 128, 0, stream>>>(SD+7*256, g_dr1+64, be_dr1+64, SC+7*128, 64, i64k);
    bna_rB<<<dim3(4096), 256, 0, stream>>>(B2, SC+7*128, nullptr, B2, 64, 1024, 1, 1048576);

    conv_rB<64,64,3,0,64,32, true,true,true,false>
        <<<dim3(16, N, 2), 256, 0, stream>>>(B2, w_dr1+24576, b_dr1+128, nullptr, SD+8*256, B1, 1024, 1024, 1);
    bnp_rB<<<1, 128, 0, stream>>>(SD+8*256, g_dr1+128, be_dr1+128, SC+8*128, 64, i64k);
    bna_rB<<<dim3(4096), 256, 0, stream>>>(B1, SC+8*128, B0, B0, 64, 1024, 0, 1048576);

    conv_rB<64,32,7,0,64,16, true,false,true,false>
        <<<dim3(16, N, 2), 256, 0, stream>>>(B0, w_deconv, b_deconv, nullptr, nullptr, out, 1024, 1024, 3);
}